// Round 1
// baseline (2987.617 us; speedup 1.0000x reference)
//
#include <hip/hip_runtime.h>
#include <math.h>

// Problem constants
constexpr int   Bb  = 2;
constexpr int   Ss  = 1024;
constexpr int   HID = 4096;
constexpr int   NH  = 32;
constexpr int   NKV = 8;
constexpr int   HD  = 128;
constexpr float SCALING = 0.0883883476483184405501f; // 128^-0.5

enum { M_Q = 0, M_K = 1, M_VT = 2, M_SC = 3, M_PV = 4, M_OUT = 5 };

// ---------------------------------------------------------------------------
// Generic tiled fp32 GEMM:  C = A (M x K, row-major) * B^T  (B is N x K, row-major)
// 64x64 tile, BK=16, 256 threads, 4x4 per thread. MODE selects epilogue scatter.
// All M,N multiples of 64; K multiple of 16 (holds for every call here).
// ---------------------------------------------------------------------------
template <int MODE>
__global__ __launch_bounds__(256) void gemm_bt(const float* __restrict__ Aall,
                                               const float* __restrict__ Ball,
                                               float* __restrict__ Call,
                                               const float* __restrict__ mask,
                                               int M, int N, int K) {
  __shared__ float As[16][68];
  __shared__ float Bs[16][68];

  const int z = blockIdx.z;
  const float* A = Aall;
  const float* Bp = Ball;
  int bidx = 0, hidx = 0;
  if (MODE == M_SC) {
    bidx = z >> 5;
    hidx = z & 31;
    A = Aall + (size_t)z * Ss * HD;                          // q[b,h]
    Bp = Ball + (size_t)(bidx * NKV + (hidx >> 2)) * Ss * HD;  // k[b,h/4]
  } else if (MODE == M_PV) {
    bidx = z >> 5;
    hidx = z & 31;
    A = Aall + (size_t)z * Ss * Ss;                           // w[b,h]
    Bp = Ball + (size_t)(bidx * NKV + (hidx >> 2)) * HD * Ss;  // vT[b,h/4]
  }

  const int tid = threadIdx.x;
  const int tx = tid & 15, ty = tid >> 4;
  const int m0 = blockIdx.y * 64, n0 = blockIdx.x * 64;
  const int lr = tid >> 2;          // 0..63 row within tile
  const int lk = (tid & 3) << 2;    // 0,4,8,12 k within K-tile

  float acc[4][4] = {};

  const float* ag = A + (size_t)(m0 + lr) * K + lk;
  const float* bg = Bp + (size_t)(n0 + lr) * K + lk;

  for (int kt = 0; kt < K; kt += 16) {
    float4 a4 = *(const float4*)(ag + kt);
    float4 b4 = *(const float4*)(bg + kt);
    __syncthreads();  // previous iteration's LDS reads complete
    As[lk + 0][lr] = a4.x; As[lk + 1][lr] = a4.y;
    As[lk + 2][lr] = a4.z; As[lk + 3][lr] = a4.w;
    Bs[lk + 0][lr] = b4.x; Bs[lk + 1][lr] = b4.y;
    Bs[lk + 2][lr] = b4.z; Bs[lk + 3][lr] = b4.w;
    __syncthreads();
#pragma unroll
    for (int k = 0; k < 16; ++k) {
      float4 av = *(const float4*)&As[k][ty << 2];
      float4 bv = *(const float4*)&Bs[k][tx << 2];
      float a[4] = {av.x, av.y, av.z, av.w};
      float b[4] = {bv.x, bv.y, bv.z, bv.w};
#pragma unroll
      for (int i = 0; i < 4; i++)
#pragma unroll
        for (int j = 0; j < 4; j++) acc[i][j] = fmaf(a[i], b[j], acc[i][j]);
    }
  }

#pragma unroll
  for (int i = 0; i < 4; i++) {
    const int m = m0 + (ty << 2) + i;
#pragma unroll
    for (int j = 0; j < 4; j++) {
      const int n = n0 + (tx << 2) + j;
      float v = acc[i][j];
      if (MODE == M_Q) {
        int b = m >> 10, s = m & 1023, h = n >> 7, d = n & 127;
        Call[(((size_t)(b * NH + h) * Ss + s) * HD) + d] = v;
      } else if (MODE == M_K) {
        int b = m >> 10, s = m & 1023, h = n >> 7, d = n & 127;
        Call[(((size_t)(b * NKV + h) * Ss + s) * HD) + d] = v;
      } else if (MODE == M_VT) {
        int b = m >> 10, s = m & 1023, h = n >> 7, d = n & 127;
        Call[(((size_t)(b * NKV + h) * HD + d) * Ss) + s] = v;
      } else if (MODE == M_SC) {
        v = v * SCALING + mask[((size_t)bidx * Ss + m) * Ss + n];
        Call[(size_t)z * Ss * Ss + (size_t)m * Ss + n] = v;
      } else if (MODE == M_PV) {
        Call[((size_t)(bidx * Ss + m)) * HID + hidx * HD + n] = v;
      } else {  // M_OUT: plain row-major
        Call[(size_t)m * N + n] = v;
      }
    }
  }
}

// ---------------------------------------------------------------------------
// RoPE + per-row (HD) asymmetric 8-bit fake-quant for q.  One wave per row.
// ---------------------------------------------------------------------------
__global__ __launch_bounds__(256) void rope_quant_q(float* __restrict__ q,
                                                    const float* __restrict__ cs,
                                                    const float* __restrict__ sn) {
  const int row = blockIdx.x * 4 + (threadIdx.x >> 6);  // 0 .. B*NH*S-1
  const int lane = threadIdx.x & 63;
  const int s = row & (Ss - 1);
  const int b = row >> 15;  // row>>10 = b*NH+h; /32
  float* p = q + (size_t)row * HD;
  const float* cp = cs + ((size_t)b * Ss + s) * HD;
  const float* sp = sn + ((size_t)b * Ss + s) * HD;
  float x1 = p[lane], x2 = p[lane + 64];
  float r1 = x1 * cp[lane] - x2 * sp[lane];
  float r2 = x2 * cp[lane + 64] + x1 * sp[lane + 64];
  float mn = fminf(0.f, fminf(r1, r2));
  float mx = fmaxf(0.f, fmaxf(r1, r2));
#pragma unroll
  for (int o = 32; o; o >>= 1) {
    mn = fminf(mn, __shfl_xor(mn, o));
    mx = fmaxf(mx, __shfl_xor(mx, o));
  }
  float rng = mx - mn;
  float scale = (rng == 0.f) ? 1.f : rng / 255.f;
  float zero = rintf(-mn / scale);
  float q1 = fminf(fmaxf(rintf(r1 / scale) + zero, 0.f), 255.f);
  float q2 = fminf(fmaxf(rintf(r2 / scale) + zero, 0.f), 255.f);
  p[lane] = (q1 - zero) * scale;
  p[lane + 64] = (q2 - zero) * scale;
}

// RoPE only for k (quant happens after mean-centering). One wave per row.
__global__ __launch_bounds__(256) void rope_k(float* __restrict__ k,
                                              const float* __restrict__ cs,
                                              const float* __restrict__ sn) {
  const int row = blockIdx.x * 4 + (threadIdx.x >> 6);  // 0 .. B*NKV*S-1
  const int lane = threadIdx.x & 63;
  const int s = row & (Ss - 1);
  const int b = row >> 13;  // row>>10 = b*NKV+h; /8
  float* p = k + (size_t)row * HD;
  const float* cp = cs + ((size_t)b * Ss + s) * HD;
  const float* sp = sn + ((size_t)b * Ss + s) * HD;
  float x1 = p[lane], x2 = p[lane + 64];
  float r1 = x1 * cp[lane] - x2 * sp[lane];
  float r2 = x2 * cp[lane + 64] + x1 * sp[lane + 64];
  p[lane] = r1;
  p[lane + 64] = r2;
}

// Mean of k over S per (b,h,d).  One 1024-thread block per (b,h).
__global__ __launch_bounds__(1024) void kmean_kernel(const float* __restrict__ k,
                                                     float* __restrict__ kmean) {
  const int bh = blockIdx.x;  // 0..15
  const int d = threadIdx.x & 127;
  const int sl = threadIdx.x >> 7;  // 0..7
  const float* p = k + (size_t)bh * Ss * HD;
  float sum = 0.f;
  for (int s = sl; s < Ss; s += 8) sum += p[(size_t)s * HD + d];
  __shared__ float lds[8][128];
  lds[sl][d] = sum;
  __syncthreads();
  if (threadIdx.x < 128) {
    float t = 0.f;
#pragma unroll
    for (int i = 0; i < 8; i++) t += lds[i][threadIdx.x];
    kmean[bh * HD + threadIdx.x] = t * (1.f / 1024.f);
  }
}

// Subtract mean + per-row quant for k. One wave per row.
__global__ __launch_bounds__(256) void k_subquant(float* __restrict__ k,
                                                  const float* __restrict__ kmean) {
  const int row = blockIdx.x * 4 + (threadIdx.x >> 6);
  const int lane = threadIdx.x & 63;
  const int bh = row >> 10;
  float* p = k + (size_t)row * HD;
  float x1 = p[lane] - kmean[bh * HD + lane];
  float x2 = p[lane + 64] - kmean[bh * HD + lane + 64];
  float mn = fminf(0.f, fminf(x1, x2));
  float mx = fmaxf(0.f, fmaxf(x1, x2));
#pragma unroll
  for (int o = 32; o; o >>= 1) {
    mn = fminf(mn, __shfl_xor(mn, o));
    mx = fmaxf(mx, __shfl_xor(mx, o));
  }
  float rng = mx - mn;
  float scale = (rng == 0.f) ? 1.f : rng / 255.f;
  float zero = rintf(-mn / scale);
  float q1 = fminf(fmaxf(rintf(x1 / scale) + zero, 0.f), 255.f);
  float q2 = fminf(fmaxf(rintf(x2 / scale) + zero, 0.f), 255.f);
  p[lane] = (q1 - zero) * scale;
  p[lane + 64] = (q2 - zero) * scale;
}

// Per-(b,h,d) quant of v over S (vT row-wise). One 256-thread block per row.
__global__ __launch_bounds__(256) void vquant(float* __restrict__ vT) {
  float* p = vT + (size_t)blockIdx.x * Ss;
  const int t = threadIdx.x;
  float4 x = ((const float4*)p)[t];
  float mn = fminf(0.f, fminf(fminf(x.x, x.y), fminf(x.z, x.w)));
  float mx = fmaxf(0.f, fmaxf(fmaxf(x.x, x.y), fmaxf(x.z, x.w)));
#pragma unroll
  for (int o = 32; o; o >>= 1) {
    mn = fminf(mn, __shfl_xor(mn, o));
    mx = fmaxf(mx, __shfl_xor(mx, o));
  }
  __shared__ float smn[4], smx[4];
  const int wid = t >> 6, lane = t & 63;
  if (lane == 0) { smn[wid] = mn; smx[wid] = mx; }
  __syncthreads();
  mn = fminf(fminf(smn[0], smn[1]), fminf(smn[2], smn[3]));
  mx = fmaxf(fmaxf(smx[0], smx[1]), fmaxf(smx[2], smx[3]));
  float rng = mx - mn;
  float scale = (rng == 0.f) ? 1.f : rng / 255.f;
  float zero = rintf(-mn / scale);
  float4 o4;
  o4.x = (fminf(fmaxf(rintf(x.x / scale) + zero, 0.f), 255.f) - zero) * scale;
  o4.y = (fminf(fmaxf(rintf(x.y / scale) + zero, 0.f), 255.f) - zero) * scale;
  o4.z = (fminf(fmaxf(rintf(x.z / scale) + zero, 0.f), 255.f) - zero) * scale;
  o4.w = (fminf(fmaxf(rintf(x.w / scale) + zero, 0.f), 255.f) - zero) * scale;
  ((float4*)p)[t] = o4;
}

// Softmax + per-row quant of w, in place (row = 1024). 256 threads per row.
__global__ __launch_bounds__(256) void softmax_quant_kernel(float* __restrict__ wbuf) {
  float* p = wbuf + (size_t)blockIdx.x * Ss;
  const int t = threadIdx.x;
  const int wid = t >> 6, lane = t & 63;
  float4 x = ((const float4*)p)[t];
  float mx = fmaxf(fmaxf(x.x, x.y), fmaxf(x.z, x.w));
#pragma unroll
  for (int o = 32; o; o >>= 1) mx = fmaxf(mx, __shfl_xor(mx, o));
  __shared__ float s1[4], s2[4], s3[4];
  if (lane == 0) s1[wid] = mx;
  __syncthreads();
  mx = fmaxf(fmaxf(s1[0], s1[1]), fmaxf(s1[2], s1[3]));
  float4 e;
  e.x = expf(x.x - mx); e.y = expf(x.y - mx);
  e.z = expf(x.z - mx); e.w = expf(x.w - mx);
  float sum = e.x + e.y + e.z + e.w;
#pragma unroll
  for (int o = 32; o; o >>= 1) sum += __shfl_xor(sum, o);
  if (lane == 0) s2[wid] = sum;
  __syncthreads();
  sum = s2[0] + s2[1] + s2[2] + s2[3];
  float inv = 1.f / sum;
  float4 pv;
  pv.x = e.x * inv; pv.y = e.y * inv; pv.z = e.z * inv; pv.w = e.w * inv;
  float pm = fmaxf(fmaxf(pv.x, pv.y), fmaxf(pv.z, pv.w));
#pragma unroll
  for (int o = 32; o; o >>= 1) pm = fmaxf(pm, __shfl_xor(pm, o));
  if (lane == 0) s3[wid] = pm;
  __syncthreads();
  pm = fmaxf(fmaxf(s3[0], s3[1]), fmaxf(s3[2], s3[3]));
  // xmin = 0 (p >= 0), so zero-point = 0
  float scale = (pm > 0.f) ? pm / 255.f : 1.f;
  float4 o4;
  o4.x = fminf(fmaxf(rintf(pv.x / scale), 0.f), 255.f) * scale;
  o4.y = fminf(fmaxf(rintf(pv.y / scale), 0.f), 255.f) * scale;
  o4.z = fminf(fmaxf(rintf(pv.z / scale), 0.f), 255.f) * scale;
  o4.w = fminf(fmaxf(rintf(pv.w / scale), 0.f), 255.f) * scale;
  ((float4*)p)[t] = o4;
}

// ---------------------------------------------------------------------------
extern "C" void kernel_launch(void* const* d_in, const int* in_sizes, int n_in,
                              void* d_out, int out_size, void* d_ws, size_t ws_size,
                              hipStream_t stream) {
  const float* hs = (const float*)d_in[0];
  const float* cosp = (const float*)d_in[1];
  const float* sinp = (const float*)d_in[2];
  const float* mask = (const float*)d_in[3];
  const float* Wq = (const float*)d_in[4];
  const float* Wk = (const float*)d_in[5];
  const float* Wv = (const float*)d_in[6];
  const float* Wo = (const float*)d_in[7];

  float* out = (float*)d_out;
  float* wout = out + (size_t)Bb * Ss * HID;  // 8,388,608 floats in

  // workspace layout (floats)
  float* q = (float*)d_ws;                                  // B*NH*S*HD  = 8,388,608
  float* k = q + (size_t)Bb * NH * Ss * HD;                 // B*NKV*S*HD = 2,097,152
  float* vT = k + (size_t)Bb * NKV * Ss * HD;               // B*NKV*HD*S = 2,097,152
  float* kmean = vT + (size_t)Bb * NKV * Ss * HD;           // B*NKV*HD   = 2,048
  float* attn = q;  // q is dead after the scores GEMM; reuse for attn (B,S,NH*HD)

  dim3 blk(256);

  // 1-3: QKV projections (A = hs 2048x4096, B = W rows, scatter epilogues)
  gemm_bt<M_Q><<<dim3(HID / 64, (Bb * Ss) / 64, 1), blk, 0, stream>>>(
      hs, Wq, q, nullptr, Bb * Ss, HID, HID);
  gemm_bt<M_K><<<dim3((NKV * HD) / 64, (Bb * Ss) / 64, 1), blk, 0, stream>>>(
      hs, Wk, k, nullptr, Bb * Ss, NKV * HD, HID);
  gemm_bt<M_VT><<<dim3((NKV * HD) / 64, (Bb * Ss) / 64, 1), blk, 0, stream>>>(
      hs, Wv, vT, nullptr, Bb * Ss, NKV * HD, HID);

  // 4-8: RoPE, mean-center, quantize
  rope_quant_q<<<(Bb * NH * Ss) / 4, blk, 0, stream>>>(q, cosp, sinp);
  rope_k<<<(Bb * NKV * Ss) / 4, blk, 0, stream>>>(k, cosp, sinp);
  kmean_kernel<<<Bb * NKV, 1024, 0, stream>>>(k, kmean);
  k_subquant<<<(Bb * NKV * Ss) / 4, blk, 0, stream>>>(k, kmean);
  vquant<<<Bb * NKV * HD, blk, 0, stream>>>(vT);

  // 9: scores = q k^T * scaling + mask  -> straight into w output slot
  gemm_bt<M_SC><<<dim3(Ss / 64, Ss / 64, Bb * NH), blk, 0, stream>>>(
      q, k, wout, mask, Ss, Ss, HD);

  // 10: softmax + quant in place on w
  softmax_quant_kernel<<<Bb * NH * Ss, blk, 0, stream>>>(wout);

  // 11: attn = w @ v   (B operand is vT rows)
  gemm_bt<M_PV><<<dim3(HD / 64, Ss / 64, Bb * NH), blk, 0, stream>>>(
      wout, vT, attn, nullptr, Ss, HD, Ss);

  // 12: out = attn @ Wo^T
  gemm_bt<M_OUT><<<dim3(HID / 64, (Bb * Ss) / 64, 1), blk, 0, stream>>>(
      attn, Wo, out, nullptr, Bb * Ss, HID, HID);
}

// Round 2
// 652.099 us; speedup vs baseline: 4.5815x; 4.5815x over previous
//
#include <hip/hip_runtime.h>
#include <math.h>
#include <stdint.h>

typedef unsigned int u32;
typedef unsigned short u16;
typedef __bf16 bf16x8 __attribute__((ext_vector_type(8)));
typedef float f32x4 __attribute__((ext_vector_type(4)));
typedef unsigned short u16x8 __attribute__((ext_vector_type(8)));
typedef unsigned short u16x4 __attribute__((ext_vector_type(4)));

constexpr int   Bb  = 2;
constexpr int   Ss  = 1024;
constexpr int   HID = 4096;
constexpr int   NH  = 32;
constexpr int   NKV = 8;
constexpr int   HD  = 128;
constexpr float SCALING = 0.0883883476483184405501f; // 128^-0.5

enum { M_QKV = 0, M_SC = 1, M_PV = 2, M_OUT = 3 };

// fp32 -> bf16 RTNE (bit trick; finite values only here)
__device__ __forceinline__ u16 f2bf(float f) {
  u32 u = __builtin_bit_cast(u32, f);
  u = u + 0x7fffu + ((u >> 16) & 1u);
  return (u16)(u >> 16);
}

// async global->LDS, 16B per lane, LDS dest = wave-uniform base + lane*16
__device__ __forceinline__ void gld_lds16(const void* g, void* l) {
  __builtin_amdgcn_global_load_lds(
      (const __attribute__((address_space(1))) u32*)(uintptr_t)g,
      (__attribute__((address_space(3))) u32*)(uintptr_t)l, 16, 0, 0);
}

// ---------------------------------------------------------------------------
// bf16 MFMA GEMM, m97 structure: 128x128 tile, BK=32, 256 threads (4 waves,
// 2x2), 16x16x32 MFMA, 4x4 fragments per wave. C = A * B^T with A[m][k],
// B^T[n][k] both K-contiguous. LDS XOR-swizzle: slot (r,q) holds global
// (r, q ^ ((r>>1)&3)) so stride-64B row reads are max 2-way (free).
// MODE selects operand resolution + epilogue scatter.
// ---------------------------------------------------------------------------
template <int MODE>
__global__ __launch_bounds__(256) void mfma_gemm(
    const u16* __restrict__ Abf_g, const float* __restrict__ Af32_g,
    const u16* __restrict__ B0, const u16* __restrict__ B1,
    const u16* __restrict__ B2,
    float* __restrict__ Cf, float* __restrict__ Ck, float* __restrict__ Cv,
    u16* __restrict__ Cb, const float* __restrict__ mask, int K) {
  __shared__ u16 As[128 * 32];
  __shared__ u16 Bs[128 * 32];

  const int tid = threadIdx.x;
  const int lane = tid & 63;
  const int wid = tid >> 6;
  const int wr = wid >> 1, wc = wid & 1;

  const int m0 = blockIdx.y * 128;
  int nloc = blockIdx.x * 128;  // column base within the logical B matrix

  const u16* Abf = nullptr;
  const float* Af = nullptr;
  const u16* Bp = nullptr;
  int which = 0, zb = 0, zh = 0, z = 0;

  if (MODE == M_QKV) {
    const int j = blockIdx.x;  // 0..47: 32 Q col-blocks, 8 K, 8 V
    if (j < 32)      { which = 0; Bp = B0 + (size_t)j * 128 * K;        nloc = j * 128; }
    else if (j < 40) { which = 1; Bp = B1 + (size_t)(j - 32) * 128 * K; nloc = (j - 32) * 128; }
    else             { which = 2; Bp = B2 + (size_t)(j - 40) * 128 * K; nloc = (j - 40) * 128; }
    Abf = Abf_g + (size_t)m0 * K;
  } else if (MODE == M_SC) {
    z = blockIdx.z; zb = z >> 5; zh = z & 31;
    Abf = Abf_g + (size_t)z * Ss * HD + (size_t)m0 * K;
    Bp = B0 + (size_t)(zb * NKV + (zh >> 2)) * Ss * HD + (size_t)nloc * K;
  } else if (MODE == M_PV) {
    z = blockIdx.z; zb = z >> 5; zh = z & 31;
    Af = Af32_g + (size_t)z * Ss * Ss + (size_t)m0 * K;  // fp32 w
    Bp = B0 + (size_t)(zb * NKV + (zh >> 2)) * HD * Ss + (size_t)nloc * K;
  } else {  // M_OUT
    Abf = Abf_g + (size_t)m0 * K;
    Bp = B0 + (size_t)nloc * K;
  }

  f32x4 acc[4][4];
#pragma unroll
  for (int i = 0; i < 4; i++)
#pragma unroll
    for (int j = 0; j < 4; j++) acc[i][j] = (f32x4){0.f, 0.f, 0.f, 0.f};

  const int sr = lane >> 2;  // row within 16-row chunk
  const int sp = lane & 3;   // 16B slot within 64B row
  const int fr = lane & 15;  // fragment row/col
  const int fq = lane >> 4;  // k-group / row-quad

  for (int kt = 0; kt < K; kt += 32) {
    __syncthreads();  // previous iteration's LDS reads complete
#pragma unroll
    for (int cc = 0; cc < 2; ++cc) {
      const int c = wid + cc * 4;     // chunk 0..7 (16 rows each)
      const int r = c * 16 + sr;      // row within 128-row tile
      const int sw = (r >> 1) & 3;
      if (MODE == M_PV) {
        // reg-stage fp32 w -> bf16 swizzled LDS
        const float* ga = Af + (size_t)r * K + kt + ((sp ^ sw) * 8);
        float4 u0 = ((const float4*)ga)[0];
        float4 u1 = ((const float4*)ga)[1];
        u16x8 t;
        t[0] = f2bf(u0.x); t[1] = f2bf(u0.y); t[2] = f2bf(u0.z); t[3] = f2bf(u0.w);
        t[4] = f2bf(u1.x); t[5] = f2bf(u1.y); t[6] = f2bf(u1.z); t[7] = f2bf(u1.w);
        *(u16x8*)&As[r * 32 + sp * 8] = t;
      } else {
        const u16* ga = Abf + (size_t)r * K + kt + ((sp ^ sw) * 8);
        gld_lds16(ga, &As[c * 512]);
      }
      const u16* gb = Bp + (size_t)r * K + kt + ((sp ^ sw) * 8);
      gld_lds16(gb, &Bs[c * 512]);
    }
    __syncthreads();  // staging visible (compiler drains vmcnt/lgkmcnt)

    bf16x8 av[4], bv[4];
#pragma unroll
    for (int f = 0; f < 4; ++f) {
      const int ra = wr * 64 + f * 16 + fr;
      av[f] = *(const bf16x8*)&As[ra * 32 + ((fq ^ ((ra >> 1) & 3)) * 8)];
      const int rb = wc * 64 + f * 16 + fr;
      bv[f] = *(const bf16x8*)&Bs[rb * 32 + ((fq ^ ((rb >> 1) & 3)) * 8)];
    }
#pragma unroll
    for (int i = 0; i < 4; i++)
#pragma unroll
      for (int j = 0; j < 4; j++)
        acc[i][j] = __builtin_amdgcn_mfma_f32_16x16x32_bf16(av[i], bv[j], acc[i][j], 0, 0, 0);
  }

  // Epilogue: C[row=(lane>>4)*4+e][col=lane&15] per 16x16 fragment
#pragma unroll
  for (int i = 0; i < 4; i++) {
#pragma unroll
    for (int j = 0; j < 4; j++) {
      const int n = nloc + wc * 64 + j * 16 + fr;
#pragma unroll
      for (int e = 0; e < 4; e++) {
        const int m = m0 + wr * 64 + i * 16 + fq * 4 + e;
        float val = acc[i][j][e];
        if (MODE == M_QKV) {
          const int b = m >> 10, s = m & 1023, h = n >> 7, d = n & 127;
          if (which == 0)      Cf[((size_t)(b * NH + h) * Ss + s) * HD + d] = val;
          else if (which == 1) Ck[((size_t)(b * NKV + h) * Ss + s) * HD + d] = val;
          else                 Cv[((size_t)(b * NKV + h) * HD + d) * Ss + s] = val;
        } else if (MODE == M_SC) {
          val = val * SCALING + mask[((size_t)zb * Ss + m) * Ss + n];
          Cf[(size_t)z * Ss * Ss + (size_t)m * Ss + n] = val;
        } else if (MODE == M_PV) {
          Cb[((size_t)(zb * Ss + m)) * HID + zh * HD + n] = f2bf(val);
        } else {  // M_OUT
          Cf[(size_t)m * HID + n] = val;
        }
      }
    }
  }
}

// ---------------------------------------------------------------------------
// fp32 -> bf16 conversion, 8 elems/thread
__global__ __launch_bounds__(256) void f32_to_bf16_k(const float* __restrict__ in,
                                                     u16* __restrict__ out, int n8) {
  const int i = blockIdx.x * 256 + threadIdx.x;
  if (i < n8) {
    float4 a = ((const float4*)in)[2 * i];
    float4 b = ((const float4*)in)[2 * i + 1];
    u16x8 t;
    t[0] = f2bf(a.x); t[1] = f2bf(a.y); t[2] = f2bf(a.z); t[3] = f2bf(a.w);
    t[4] = f2bf(b.x); t[5] = f2bf(b.y); t[6] = f2bf(b.z); t[7] = f2bf(b.w);
    ((u16x8*)out)[i] = t;
  }
}

// RoPE + per-row asymmetric 8-bit fake-quant for q -> bf16. One wave per row.
__global__ __launch_bounds__(256) void rope_quant_q(const float* __restrict__ q,
                                                    u16* __restrict__ qb,
                                                    const float* __restrict__ cs,
                                                    const float* __restrict__ sn) {
  const int row = blockIdx.x * 4 + (threadIdx.x >> 6);  // 0 .. B*NH*S-1
  const int lane = threadIdx.x & 63;
  const int s = row & (Ss - 1);
  const int b = row >> 15;
  const float* p = q + (size_t)row * HD;
  const float* cp = cs + ((size_t)b * Ss + s) * HD;
  const float* sp = sn + ((size_t)b * Ss + s) * HD;
  float x1 = p[lane], x2 = p[lane + 64];
  float r1 = x1 * cp[lane] - x2 * sp[lane];
  float r2 = x2 * cp[lane + 64] + x1 * sp[lane + 64];
  float mn = fminf(0.f, fminf(r1, r2));
  float mx = fmaxf(0.f, fmaxf(r1, r2));
#pragma unroll
  for (int o = 32; o; o >>= 1) {
    mn = fminf(mn, __shfl_xor(mn, o));
    mx = fmaxf(mx, __shfl_xor(mx, o));
  }
  float rng = mx - mn;
  float scale = (rng == 0.f) ? 1.f : rng / 255.f;
  float zero = rintf(-mn / scale);
  float q1 = fminf(fmaxf(rintf(r1 / scale) + zero, 0.f), 255.f);
  float q2 = fminf(fmaxf(rintf(r2 / scale) + zero, 0.f), 255.f);
  qb[(size_t)row * HD + lane] = f2bf((q1 - zero) * scale);
  qb[(size_t)row * HD + lane + 64] = f2bf((q2 - zero) * scale);
}

// RoPE only for k (quant after mean-centering). One wave per row, in place.
__global__ __launch_bounds__(256) void rope_k(float* __restrict__ k,
                                              const float* __restrict__ cs,
                                              const float* __restrict__ sn) {
  const int row = blockIdx.x * 4 + (threadIdx.x >> 6);  // 0 .. B*NKV*S-1
  const int lane = threadIdx.x & 63;
  const int s = row & (Ss - 1);
  const int b = row >> 13;
  float* p = k + (size_t)row * HD;
  const float* cp = cs + ((size_t)b * Ss + s) * HD;
  const float* sp = sn + ((size_t)b * Ss + s) * HD;
  float x1 = p[lane], x2 = p[lane + 64];
  float r1 = x1 * cp[lane] - x2 * sp[lane];
  float r2 = x2 * cp[lane + 64] + x1 * sp[lane + 64];
  p[lane] = r1;
  p[lane + 64] = r2;
}

// Mean of k over S per (b,h,d). One 1024-thread block per (b,h).
__global__ __launch_bounds__(1024) void kmean_kernel(const float* __restrict__ k,
                                                     float* __restrict__ kmean) {
  const int bh = blockIdx.x;
  const int d = threadIdx.x & 127;
  const int sl = threadIdx.x >> 7;
  const float* p = k + (size_t)bh * Ss * HD;
  float sum = 0.f;
  for (int s = sl; s < Ss; s += 8) sum += p[(size_t)s * HD + d];
  __shared__ float lds[8][128];
  lds[sl][d] = sum;
  __syncthreads();
  if (threadIdx.x < 128) {
    float t = 0.f;
#pragma unroll
    for (int i = 0; i < 8; i++) t += lds[i][threadIdx.x];
    kmean[bh * HD + threadIdx.x] = t * (1.f / 1024.f);
  }
}

// Subtract mean + per-row quant for k -> bf16. One wave per row.
__global__ __launch_bounds__(256) void k_subquant(const float* __restrict__ k,
                                                  u16* __restrict__ kb,
                                                  const float* __restrict__ kmean) {
  const int row = blockIdx.x * 4 + (threadIdx.x >> 6);
  const int lane = threadIdx.x & 63;
  const int bh = row >> 10;
  const float* p = k + (size_t)row * HD;
  float x1 = p[lane] - kmean[bh * HD + lane];
  float x2 = p[lane + 64] - kmean[bh * HD + lane + 64];
  float mn = fminf(0.f, fminf(x1, x2));
  float mx = fmaxf(0.f, fmaxf(x1, x2));
#pragma unroll
  for (int o = 32; o; o >>= 1) {
    mn = fminf(mn, __shfl_xor(mn, o));
    mx = fmaxf(mx, __shfl_xor(mx, o));
  }
  float rng = mx - mn;
  float scale = (rng == 0.f) ? 1.f : rng / 255.f;
  float zero = rintf(-mn / scale);
  float q1 = fminf(fmaxf(rintf(x1 / scale) + zero, 0.f), 255.f);
  float q2 = fminf(fmaxf(rintf(x2 / scale) + zero, 0.f), 255.f);
  kb[(size_t)row * HD + lane] = f2bf((q1 - zero) * scale);
  kb[(size_t)row * HD + lane + 64] = f2bf((q2 - zero) * scale);
}

// Per-(b,h,d) quant of v over S (vT rows) -> bf16. One block per row.
__global__ __launch_bounds__(256) void vquant(const float* __restrict__ vT,
                                              u16* __restrict__ vTb) {
  const float* p = vT + (size_t)blockIdx.x * Ss;
  const int t = threadIdx.x;
  float4 x = ((const float4*)p)[t];
  float mn = fminf(0.f, fminf(fminf(x.x, x.y), fminf(x.z, x.w)));
  float mx = fmaxf(0.f, fmaxf(fmaxf(x.x, x.y), fmaxf(x.z, x.w)));
#pragma unroll
  for (int o = 32; o; o >>= 1) {
    mn = fminf(mn, __shfl_xor(mn, o));
    mx = fmaxf(mx, __shfl_xor(mx, o));
  }
  __shared__ float smn[4], smx[4];
  const int wid = t >> 6, lane = t & 63;
  if (lane == 0) { smn[wid] = mn; smx[wid] = mx; }
  __syncthreads();
  mn = fminf(fminf(smn[0], smn[1]), fminf(smn[2], smn[3]));
  mx = fmaxf(fmaxf(smx[0], smx[1]), fmaxf(smx[2], smx[3]));
  float rng = mx - mn;
  float scale = (rng == 0.f) ? 1.f : rng / 255.f;
  float zero = rintf(-mn / scale);
  u16x4 o4;
  o4[0] = f2bf((fminf(fmaxf(rintf(x.x / scale) + zero, 0.f), 255.f) - zero) * scale);
  o4[1] = f2bf((fminf(fmaxf(rintf(x.y / scale) + zero, 0.f), 255.f) - zero) * scale);
  o4[2] = f2bf((fminf(fmaxf(rintf(x.z / scale) + zero, 0.f), 255.f) - zero) * scale);
  o4[3] = f2bf((fminf(fmaxf(rintf(x.w / scale) + zero, 0.f), 255.f) - zero) * scale);
  ((u16x4*)vTb)[(size_t)blockIdx.x * 256 + t] = o4;
}

// Softmax + per-row quant of w, in place on fp32 output. 256 threads/row.
__global__ __launch_bounds__(256) void softmax_quant_kernel(float* __restrict__ wbuf) {
  float* p = wbuf + (size_t)blockIdx.x * Ss;
  const int t = threadIdx.x;
  const int wid = t >> 6, lane = t & 63;
  float4 x = ((const float4*)p)[t];
  float mx = fmaxf(fmaxf(x.x, x.y), fmaxf(x.z, x.w));
#pragma unroll
  for (int o = 32; o; o >>= 1) mx = fmaxf(mx, __shfl_xor(mx, o));
  __shared__ float s1[4], s2[4], s3[4];
  if (lane == 0) s1[wid] = mx;
  __syncthreads();
  mx = fmaxf(fmaxf(s1[0], s1[1]), fmaxf(s1[2], s1[3]));
  float4 e;
  e.x = expf(x.x - mx); e.y = expf(x.y - mx);
  e.z = expf(x.z - mx); e.w = expf(x.w - mx);
  float sum = e.x + e.y + e.z + e.w;
#pragma unroll
  for (int o = 32; o; o >>= 1) sum += __shfl_xor(sum, o);
  if (lane == 0) s2[wid] = sum;
  __syncthreads();
  sum = s2[0] + s2[1] + s2[2] + s2[3];
  float inv = 1.f / sum;
  float4 pv;
  pv.x = e.x * inv; pv.y = e.y * inv; pv.z = e.z * inv; pv.w = e.w * inv;
  float pm = fmaxf(fmaxf(pv.x, pv.y), fmaxf(pv.z, pv.w));
#pragma unroll
  for (int o = 32; o; o >>= 1) pm = fmaxf(pm, __shfl_xor(pm, o));
  if (lane == 0) s3[wid] = pm;
  __syncthreads();
  pm = fmaxf(fmaxf(s3[0], s3[1]), fmaxf(s3[2], s3[3]));
  float scale = (pm > 0.f) ? pm / 255.f : 1.f;
  float4 o4;
  o4.x = fminf(fmaxf(rintf(pv.x / scale), 0.f), 255.f) * scale;
  o4.y = fminf(fmaxf(rintf(pv.y / scale), 0.f), 255.f) * scale;
  o4.z = fminf(fmaxf(rintf(pv.z / scale), 0.f), 255.f) * scale;
  o4.w = fminf(fmaxf(rintf(pv.w / scale), 0.f), 255.f) * scale;
  ((float4*)p)[t] = o4;
}

// ---------------------------------------------------------------------------
extern "C" void kernel_launch(void* const* d_in, const int* in_sizes, int n_in,
                              void* d_out, int out_size, void* d_ws, size_t ws_size,
                              hipStream_t stream) {
  const float* hs = (const float*)d_in[0];
  const float* cosp = (const float*)d_in[1];
  const float* sinp = (const float*)d_in[2];
  const float* mask = (const float*)d_in[3];
  const float* Wq = (const float*)d_in[4];
  const float* Wk = (const float*)d_in[5];
  const float* Wv = (const float*)d_in[6];
  const float* Wo = (const float*)d_in[7];

  float* out = (float*)d_out;
  float* wout = out + (size_t)Bb * Ss * HID;  // w output region (fp32)

  // workspace layout (~176 MB)
  char* wsp = (char*)d_ws;
  auto alloc = [&](size_t bytes) {
    char* p = wsp;
    wsp += (bytes + 255) & ~(size_t)255;
    return p;
  };
  float* q     = (float*)alloc((size_t)Bb * NH * Ss * HD * 4);   // 33.6 MB
  float* k     = (float*)alloc((size_t)Bb * NKV * Ss * HD * 4);  // 8.4 MB
  float* vT    = (float*)alloc((size_t)Bb * NKV * Ss * HD * 4);  // 8.4 MB
  float* kmean = (float*)alloc((size_t)Bb * NKV * HD * 4);
  u16* hsb = (u16*)alloc((size_t)Bb * Ss * HID * 2);             // 16.8 MB
  u16* qb  = (u16*)alloc((size_t)Bb * NH * Ss * HD * 2);         // 16.8 MB
  u16* kb  = (u16*)alloc((size_t)Bb * NKV * Ss * HD * 2);        // 4.2 MB
  u16* vTb = (u16*)alloc((size_t)Bb * NKV * Ss * HD * 2);        // 4.2 MB
  u16* Wqb = (u16*)alloc((size_t)NH * HD * HID * 2);             // 33.6 MB
  u16* Wkb = (u16*)alloc((size_t)NKV * HD * HID * 2);            // 8.4 MB
  u16* Wvb = (u16*)alloc((size_t)NKV * HD * HID * 2);            // 8.4 MB
  u16* Wob = (u16*)alloc((size_t)HID * NH * HD * 2);             // 33.6 MB
  u16* attnb = (u16*)q;  // q fp32 dead after rope_quant_q; reuse for attn bf16

  // fp32 -> bf16 conversions
  f32_to_bf16_k<<<(Bb * Ss * HID / 8 + 255) / 256, 256, 0, stream>>>(hs, hsb, Bb * Ss * HID / 8);
  f32_to_bf16_k<<<(NH * HD * HID / 8 + 255) / 256, 256, 0, stream>>>(Wq, Wqb, NH * HD * HID / 8);
  f32_to_bf16_k<<<(NKV * HD * HID / 8 + 255) / 256, 256, 0, stream>>>(Wk, Wkb, NKV * HD * HID / 8);
  f32_to_bf16_k<<<(NKV * HD * HID / 8 + 255) / 256, 256, 0, stream>>>(Wv, Wvb, NKV * HD * HID / 8);
  f32_to_bf16_k<<<(HID * NH * HD / 8 + 255) / 256, 256, 0, stream>>>(Wo, Wob, HID * NH * HD / 8);

  // fused Q/K/V projection (48 col-blocks: 32 Q, 8 K, 8 V)
  mfma_gemm<M_QKV><<<dim3(48, 16, 1), 256, 0, stream>>>(
      hsb, nullptr, Wqb, Wkb, Wvb, q, k, vT, nullptr, nullptr, HID);

  // RoPE / mean-center / quantize
  rope_quant_q<<<(Bb * NH * Ss) / 4, 256, 0, stream>>>(q, qb, cosp, sinp);
  rope_k<<<(Bb * NKV * Ss) / 4, 256, 0, stream>>>(k, cosp, sinp);
  kmean_kernel<<<Bb * NKV, 1024, 0, stream>>>(k, kmean);
  k_subquant<<<(Bb * NKV * Ss) / 4, 256, 0, stream>>>(k, kb, kmean);
  vquant<<<Bb * NKV * HD, 256, 0, stream>>>(vT, vTb);

  // scores = q k^T * scaling + mask -> w output slot (fp32)
  mfma_gemm<M_SC><<<dim3(8, 8, Bb * NH), 256, 0, stream>>>(
      qb, nullptr, kb, nullptr, nullptr, wout, nullptr, nullptr, nullptr, mask, HD);

  // softmax + quant in place on w
  softmax_quant_kernel<<<Bb * NH * Ss, 256, 0, stream>>>(wout);

  // attn = w @ v (A = fp32 w reg-staged to bf16; B = vT bf16) -> attn bf16
  mfma_gemm<M_PV><<<dim3(1, 8, Bb * NH), 256, 0, stream>>>(
      nullptr, wout, vTb, nullptr, nullptr, nullptr, nullptr, nullptr, attnb, nullptr, Ss);

  // out = attn @ Wo^T (fp32 out)
  mfma_gemm<M_OUT><<<dim3(32, 16, 1), 256, 0, stream>>>(
      attnb, nullptr, Wob, nullptr, nullptr, out, nullptr, nullptr, nullptr, nullptr, HID);
}